// Round 2
// baseline (167.442 us; speedup 1.0000x reference)
//
#include <hip/hip_runtime.h>
#include <hip/hip_bf16.h>

typedef float f4vec  __attribute__((ext_vector_type(4)));
typedef float f16vec __attribute__((ext_vector_type(16)));
typedef short s8vec  __attribute__((ext_vector_type(8)));

#define B_DIM 64
#define N_DIM 64
#define D_DIM 9216
#define SPLIT 8
#define CHUNK 1152        // D_DIM / SPLIT
#define NSTEP (CHUNK / 64)  // 18

// ws layout (bytes):
//   Spart    @ 0        : 64*8*4096*4 = 8388608
//   meanPart @ 8388608  : 64*8*64*4   = 131072
//   Cout     @ 8519680  : 64*64*4     = 16384   (c = inv_L @ mean, fp32)
//   Mb(bf16) @ 8536064  : 64*4096*2   = 524288  (M = inv_L - I, row-major)

__device__ __forceinline__ short f2bf(float f) {
  union { __hip_bfloat16 h; short s; } u;
  u.h = __float2bfloat16(f);
  return u.s;
}

// ---------------- Kernel 1: partial Gram + row-sum partials ----------------
// Swizzled LDS tile: element (r,c) at r*64 + (((c>>2) ^ (r&15))<<2) + (c&3).
// Register-prefetch double buffer: next step's 16 floats loaded right after
// the LDS-ready barrier, hiding HBM latency under cvt+MFMA.
__global__ __launch_bounds__(256) void k_cov_partial(
    const float* __restrict__ x, float* __restrict__ Spart,
    float* __restrict__ meanPart) {
  const int s = blockIdx.x, b = blockIdx.y;
  const int t = threadIdx.x;
  const int lane = t & 63, w = t >> 6;
  const int wr = w >> 1, wc = w & 1;
  const int hi = lane >> 5;

  __shared__ float T[64 * 64];

  const float* xb = x + (size_t)b * N_DIM * D_DIM + (size_t)s * CHUNK;
  const int jrow = t >> 2, q = t & 3;
  const float* xrow = xb + (size_t)jrow * D_DIM;

  f16vec acc;
#pragma unroll
  for (int r = 0; r < 16; ++r) acc[r] = 0.0f;
  float msum = 0.0f;

  const int r_a = 32 * wr + (lane & 31);
  const int r_b = 32 * wc + (lane & 31);

  f4vec v[4];
#pragma unroll
  for (int i = 0; i < 4; ++i)
    v[i] = *reinterpret_cast<const f4vec*>(xrow + (i * 4 + q) * 4);

  for (int step = 0; step < NSTEP; ++step) {
    __syncthreads();  // previous step's frag reads done; LDS free
#pragma unroll
    for (int i = 0; i < 4; ++i) {
      const int f = i * 4 + q;
      msum += v[i].x + v[i].y + v[i].z + v[i].w;
      *reinterpret_cast<f4vec*>(&T[jrow * 64 + ((f ^ (jrow & 15)) << 2)]) = v[i];
    }
    __syncthreads();  // tile ready
    if (step + 1 < NSTEP) {
      const float* xn = xrow + (step + 1) * 64;
#pragma unroll
      for (int i = 0; i < 4; ++i)
        v[i] = *reinterpret_cast<const f4vec*>(xn + (i * 4 + q) * 4);
    }
#pragma unroll
    for (int ks = 0; ks < 4; ++ks) {
      const int c0 = ks * 4 + hi * 2;
      f4vec a0 = *reinterpret_cast<const f4vec*>(
          &T[r_a * 64 + ((c0 ^ (r_a & 15)) << 2)]);
      f4vec a1 = *reinterpret_cast<const f4vec*>(
          &T[r_a * 64 + (((c0 + 1) ^ (r_a & 15)) << 2)]);
      f4vec b0 = *reinterpret_cast<const f4vec*>(
          &T[r_b * 64 + ((c0 ^ (r_b & 15)) << 2)]);
      f4vec b1 = *reinterpret_cast<const f4vec*>(
          &T[r_b * 64 + (((c0 + 1) ^ (r_b & 15)) << 2)]);
      s8vec af, bf;
      af[0]=f2bf(a0.x); af[1]=f2bf(a0.y); af[2]=f2bf(a0.z); af[3]=f2bf(a0.w);
      af[4]=f2bf(a1.x); af[5]=f2bf(a1.y); af[6]=f2bf(a1.z); af[7]=f2bf(a1.w);
      bf[0]=f2bf(b0.x); bf[1]=f2bf(b0.y); bf[2]=f2bf(b0.z); bf[3]=f2bf(b0.w);
      bf[4]=f2bf(b1.x); bf[5]=f2bf(b1.y); bf[6]=f2bf(b1.z); bf[7]=f2bf(b1.w);
      acc = __builtin_amdgcn_mfma_f32_32x32x16_bf16(af, bf, acc, 0, 0, 0);
    }
  }

  msum += __shfl_xor(msum, 1);
  msum += __shfl_xor(msum, 2);
  if (q == 0) meanPart[(b * SPLIT + s) * 64 + jrow] = msum;

  float* Sp = Spart + (size_t)(b * SPLIT + s) * 4096;
#pragma unroll
  for (int r = 0; r < 16; ++r) {
    const int i = 32 * wr + (r & 3) + 8 * (r >> 2) + 4 * hi;
    const int j = 32 * wc + (lane & 31);
    Sp[i * 64 + j] = acc[r];
  }
}

// ---------------- Kernel 2: reduce -> cov -> chol -> inv_L -> M, c ---------
__global__ __launch_bounds__(256) void k_chol_inv(
    const float* __restrict__ Spart, const float* __restrict__ meanPart,
    unsigned short* __restrict__ Mb, float* __restrict__ Cout) {
  const int b = blockIdx.x;
  const int t = threadIdx.x;

  __shared__ float A[64 * 68];   // pitch 68: f4-aligned, bank-offset rows
  __shared__ float L[64 * 68];
  __shared__ float X[64 * 68];
  __shared__ float mean[64];

  if (t < 64) {
    float mm = 0.0f;
    for (int p = 0; p < SPLIT; ++p) mm += meanPart[(b * SPLIT + p) * 64 + t];
    mean[t] = mm * (1.0f / D_DIM);
  }
  __syncthreads();

  const float Df = (float)D_DIM;
  const float invD1 = 1.0f / (float)(D_DIM - 1);
  for (int v4 = t; v4 < 1024; v4 += 256) {
    f4vec ss;
    ss.x = ss.y = ss.z = ss.w = 0.0f;
    for (int p = 0; p < SPLIT; ++p)
      ss += reinterpret_cast<const f4vec*>(
          Spart + (size_t)(b * SPLIT + p) * 4096)[v4];
    const int e = v4 * 4, i = e >> 6, j = e & 63;
    const float mi = mean[i] * Df;
    f4vec res;
    res.x = (ss.x - mi * mean[j + 0]) * invD1;
    res.y = (ss.y - mi * mean[j + 1]) * invD1;
    res.z = (ss.z - mi * mean[j + 2]) * invD1;
    res.w = (ss.w - mi * mean[j + 3]) * invD1;
    *reinterpret_cast<f4vec*>(&A[i * 68 + j]) = res;
  }
  __syncthreads();

  // Deferred-scale right-looking Cholesky: ONE barrier per step.
  // Updates use unscaled column k with 1/dv; scaled L goes to a separate
  // array (no read/write race within a step).
  const int ci = t & 63, cg = t >> 6;
  for (int k = 0; k < 64; ++k) {
    const float dv = A[k * 68 + k];
    const float inv = 1.0f / dv;
    if (cg == 0 && ci >= k) {
      const float sdv = sqrtf(dv);
      L[ci * 68 + k] = (ci == k) ? sdv : A[ci * 68 + k] * (sdv * inv);
    }
    if (ci > k) {
      const float aik = A[ci * 68 + k] * inv;
      for (int j = k + 1 + cg; j <= ci; j += 4)
        A[ci * 68 + j] -= aik * A[j * 68 + k];
    }
    __syncthreads();
  }

  // Forward-substitution inverse: columns are independent; each column is
  // owned by one 4-lane group -> wave-lockstep, NO barriers in the loop.
  const int c = t >> 2, sl = t & 3;
  if (sl == 0) X[c * 68 + c] = 1.0f / L[c * 68 + c];
  for (int i = 1; i < 64; ++i) {
    float sum = 0.0f;
    if (c < i) {
      for (int j = c + sl; j < i; j += 4) sum += L[i * 68 + j] * X[j * 68 + c];
    }
    sum += __shfl_xor(sum, 1);
    sum += __shfl_xor(sum, 2);
    if (c < i && sl == 0) X[i * 68 + c] = -sum / L[i * 68 + i];
  }
  __syncthreads();

  // c = inv_L @ mean (for the mean-fold in k3): 4 lanes per row.
  {
    const int i = t >> 2;
    float s2 = 0.0f;
    for (int j = sl; j <= i; j += 4) s2 += X[i * 68 + j] * mean[j];
    s2 += __shfl_xor(s2, 1);
    s2 += __shfl_xor(s2, 2);
    if (sl == 0) Cout[b * 64 + i] = s2;
  }

  // M = inv_L - I, bf16 row-major.
  for (int e = t; e < 4096; e += 256) {
    const int i = e >> 6, j = e & 63;
    float v = (i > j) ? X[i * 68 + j] : (i == j ? X[i * 68 + i] - 1.0f : 0.0f);
    Mb[(size_t)b * 4096 + e] = (unsigned short)f2bf(v);
  }
}

// ---------------- Kernel 3: out = x + M@x - c*1^T  (LDS-free) --------------
// B-fragment of 32x32x16 MFMA = 8 k-consecutive rows at one column: loaded
// directly from global (lanes 0-31 = consecutive d -> coalesced 128B).
// x is L3-resident after k1; epilogue reloads hit L1/L2.
__global__ __launch_bounds__(256) void k_whiten(
    const float* __restrict__ x, const float* __restrict__ Cvec,
    const unsigned short* __restrict__ Mb, float* __restrict__ out) {
  const int b = blockIdx.y;
  const int t = threadIdx.x;
  const int wid = t >> 6, lane = t & 63;
  const int lo = lane & 31, hi = lane >> 5;

  s8vec mfrag[2][4];
  const unsigned short* Mbb = Mb + (size_t)b * 4096;
#pragma unroll
  for (int wr = 0; wr < 2; ++wr)
#pragma unroll
    for (int ks = 0; ks < 4; ++ks)
      mfrag[wr][ks] = *reinterpret_cast<const s8vec*>(
          Mbb + (32 * wr + lo) * 64 + ks * 16 + hi * 8);

  float cv[2][16];
  const float* cb = Cvec + b * 64;
#pragma unroll
  for (int wr = 0; wr < 2; ++wr)
#pragma unroll
    for (int r = 0; r < 16; ++r)
      cv[wr][r] = cb[32 * wr + (r & 3) + 8 * (r >> 2) + 4 * hi];

  const float* xb = x + (size_t)b * N_DIM * D_DIM;
  float* ob = out + (size_t)b * N_DIM * D_DIM;

#pragma unroll
  for (int n = 0; n < 2; ++n) {
    const int d0 = blockIdx.x * 256 + wid * 64 + n * 32;
    f16vec acc0, acc1;
#pragma unroll
    for (int r = 0; r < 16; ++r) { acc0[r] = 0.0f; acc1[r] = 0.0f; }

#pragma unroll
    for (int ks = 0; ks < 4; ++ks) {
      const float* colp = xb + (size_t)(16 * ks + 8 * hi) * D_DIM + d0 + lo;
      s8vec bf;
#pragma unroll
      for (int e = 0; e < 8; ++e) bf[e] = f2bf(colp[(size_t)e * D_DIM]);
      acc0 = __builtin_amdgcn_mfma_f32_32x32x16_bf16(mfrag[0][ks], bf, acc0, 0, 0, 0);
      acc1 = __builtin_amdgcn_mfma_f32_32x32x16_bf16(mfrag[1][ks], bf, acc1, 0, 0, 0);
    }

#pragma unroll
    for (int r = 0; r < 16; ++r) {
      const int row = (r & 3) + 8 * (r >> 2) + 4 * hi;
      const size_t off0 = (size_t)row * D_DIM + d0 + lo;
      ob[off0] = acc0[r] + xb[off0] - cv[0][r];
      const size_t off1 = (size_t)(row + 32) * D_DIM + d0 + lo;
      ob[off1] = acc1[r] + xb[off1] - cv[1][r];
    }
  }
}

extern "C" void kernel_launch(void* const* d_in, const int* in_sizes, int n_in,
                              void* d_out, int out_size, void* d_ws,
                              size_t ws_size, hipStream_t stream) {
  const float* x = (const float*)d_in[0];
  float* out = (float*)d_out;
  char* ws = (char*)d_ws;

  float* Spart = (float*)ws;                            // 8 MB
  float* meanPart = (float*)(ws + 8388608);             // 128 KB
  float* Cout = (float*)(ws + 8519680);                 // 16 KB
  unsigned short* Mb = (unsigned short*)(ws + 8536064); // 512 KB

  k_cov_partial<<<dim3(SPLIT, B_DIM), 256, 0, stream>>>(x, Spart, meanPart);
  k_chol_inv<<<dim3(B_DIM), 256, 0, stream>>>(Spart, meanPart, Mb, Cout);
  k_whiten<<<dim3(D_DIM / 256, B_DIM), 256, 0, stream>>>(x, Cout, Mb, out);
}